// Round 1
// baseline (69.308 us; speedup 1.0000x reference)
//
#include <hip/hip_runtime.h>
#include <hip/hip_bf16.h>
#include <type_traits>

// Problem constants (from reference)
// B=2, S=2048, E=1024, H=16, D=64. out = x @ M^T + c with M = Wo @ Wv_sub.
#define MROWS 4096   // B*S
#define EDIM  1024

typedef __attribute__((ext_vector_type(8))) __bf16 bf16x8;
typedef __attribute__((ext_vector_type(4))) float f32x4;
typedef __attribute__((ext_vector_type(8))) unsigned short ushort8;

__device__ __forceinline__ unsigned short f2bf(float f) {
    unsigned u = __builtin_bit_cast(unsigned, f);
    u += 0x7FFFu + ((u >> 16) & 1u);   // round-to-nearest-even
    return (unsigned short)(u >> 16);
}

__device__ __forceinline__ void async_load16(const void* g, void* l) {
    __builtin_amdgcn_global_load_lds(
        (const __attribute__((address_space(1))) void*)g,
        (__attribute__((address_space(3))) void*)l, 16, 0, 0);
}

// ---------------- cast f32 -> bf16, 8 elems/thread ----------------
__global__ __launch_bounds__(256) void cast_f32_bf16(
    const float* __restrict__ in, unsigned short* __restrict__ out, int n8)
{
    int i = blockIdx.x * blockDim.x + threadIdx.x;
    if (i >= n8) return;
    const float4* p = (const float4*)in + (size_t)i * 2;
    float4 a = p[0], b = p[1];
    ushort8 r;
    r[0] = f2bf(a.x); r[1] = f2bf(a.y); r[2] = f2bf(a.z); r[3] = f2bf(a.w);
    r[4] = f2bf(b.x); r[5] = f2bf(b.y); r[6] = f2bf(b.z); r[7] = f2bf(b.w);
    *((ushort8*)out + i) = r;
}

// ---------------- gather V-rows of Wqkv, transpose, cast ----------------
// WvT[e, k] = bf16( Wqkv[ (k/64)*192 + 128 + (k%64), e ] ), both 1024x1024.
__global__ __launch_bounds__(256) void build_wvt(
    const float* __restrict__ Wqkv, unsigned short* __restrict__ WvT)
{
    __shared__ unsigned short tile[64][65];
    const int tx = threadIdx.x;        // 0..63
    const int ty = threadIdx.y;        // 0..3
    const int kBase = blockIdx.y * 64, eBase = blockIdx.x * 64;
    #pragma unroll
    for (int r = ty; r < 64; r += 4) {
        int k = kBase + r;
        int j = ((k >> 6) * 192) + 128 + (k & 63);
        tile[r][tx] = f2bf(Wqkv[(size_t)j * EDIM + eBase + tx]);
    }
    __syncthreads();
    #pragma unroll
    for (int r = ty; r < 64; r += 4) {
        WvT[(size_t)(eBase + r) * EDIM + kBase + tx] = tile[tx][r];
    }
}

// ---------------- c[i] = bo[i] + sum_k Wo[i,k] * bqkv[jmap(k)] ----------------
__global__ __launch_bounds__(64) void compute_c(
    const float* __restrict__ Wo, const float* __restrict__ bqkv,
    const float* __restrict__ bo, float* __restrict__ c)
{
    const int i = blockIdx.x;
    const int l = threadIdx.x;
    float s = 0.f;
    for (int k = l; k < EDIM; k += 64) {
        int j = ((k >> 6) * 192) + 128 + (k & 63);
        s += Wo[(size_t)i * EDIM + k] * bqkv[j];
    }
    #pragma unroll
    for (int off = 32; off > 0; off >>= 1) s += __shfl_down(s, off);
    if (l == 0) c[i] = s + bo[i];
}

// ---------------- B^T-form bf16 MFMA GEMM ----------------
// C[m,n] = sum_k A[m,k] * B[n,k]  (+ bias[n] if BIAS). A: Mdim x Kdim row-major,
// B: Ndim x Kdim row-major, bf16 bits in ushort. 128x128 tile, BK=64, 4 waves.
template<bool BIAS, typename OUT_T>
__global__ __launch_bounds__(256, 2) void gemm_bt(
    const unsigned short* __restrict__ A, const unsigned short* __restrict__ B,
    OUT_T* __restrict__ C, const float* __restrict__ bias,
    int Mdim, int Ndim, int Kdim)
{
    constexpr int BM = 128, BN = 128, BK = 64;
    __shared__ unsigned short As[BM * BK];
    __shared__ unsigned short Bs[BN * BK];

    const int t = threadIdx.x;
    const int bm = blockIdx.x, bn = blockIdx.y;
    const int lane = t & 63, wave = t >> 6;
    const int wr = wave >> 1, wc = wave & 1;

    const int rsub = t >> 3;          // 0..31 (row within 32-row staging pass)
    const int kb   = (t & 7) * 8;     // bf16-element offset within BK

    const unsigned short* Ag = A + (size_t)(bm * BM + rsub) * Kdim + kb;
    const unsigned short* Bg = B + (size_t)(bn * BN + rsub) * Kdim + kb;

    f32x4 acc[4][4] = {};

    for (int k0 = 0; k0 < Kdim; k0 += BK) {
        __syncthreads();
        #pragma unroll
        for (int p = 0; p < 4; ++p)
            async_load16(Ag + (size_t)(p * 32) * Kdim + k0, &As[(rsub + p * 32) * BK + kb]);
        #pragma unroll
        for (int p = 0; p < 4; ++p)
            async_load16(Bg + (size_t)(p * 32) * Kdim + k0, &Bs[(rsub + p * 32) * BK + kb]);
        __syncthreads();

        #pragma unroll
        for (int ks = 0; ks < 2; ++ks) {
            bf16x8 a[4], b[4];
            #pragma unroll
            for (int mi = 0; mi < 4; ++mi)
                a[mi] = *(const bf16x8*)&As[(wr * 64 + mi * 16 + (lane & 15)) * BK + ks * 32 + (lane >> 4) * 8];
            #pragma unroll
            for (int ni = 0; ni < 4; ++ni)
                b[ni] = *(const bf16x8*)&Bs[(wc * 64 + ni * 16 + (lane & 15)) * BK + ks * 32 + (lane >> 4) * 8];
            #pragma unroll
            for (int mi = 0; mi < 4; ++mi)
                #pragma unroll
                for (int ni = 0; ni < 4; ++ni)
                    acc[mi][ni] = __builtin_amdgcn_mfma_f32_16x16x32_bf16(
                        a[mi], b[ni], acc[mi][ni], 0, 0, 0);
        }
    }

    // Epilogue. C/D layout (verified m89/m91): col = lane&15, row = (lane>>4)*4 + reg.
    const int crow0 = bm * BM + wr * 64 + (lane >> 4) * 4;
    const int ccol0 = bn * BN + wc * 64 + (lane & 15);
    #pragma unroll
    for (int mi = 0; mi < 4; ++mi) {
        #pragma unroll
        for (int ni = 0; ni < 4; ++ni) {
            const int col = ccol0 + ni * 16;
            float bv = 0.f;
            if constexpr (BIAS) bv = bias[col];
            #pragma unroll
            for (int i = 0; i < 4; ++i) {
                const int row = crow0 + mi * 16 + i;
                float val = acc[mi][ni][i] + bv;
                if constexpr (std::is_same<OUT_T, float>::value)
                    C[(size_t)row * Ndim + col] = val;
                else
                    C[(size_t)row * Ndim + col] = f2bf(val);
            }
        }
    }
}

extern "C" void kernel_launch(void* const* d_in, const int* in_sizes, int n_in,
                              void* d_out, int out_size, void* d_ws, size_t ws_size,
                              hipStream_t stream) {
    const float* x    = (const float*)d_in[0];   // (2,2048,1024)
    const float* Wqkv = (const float*)d_in[1];   // (3072,1024)
    const float* bqkv = (const float*)d_in[2];   // (3072,)
    const float* Wo   = (const float*)d_in[3];   // (1024,1024)
    const float* bo   = (const float*)d_in[4];   // (1024,)
    float* out = (float*)d_out;                  // (2,2048,1024) f32

    char* ws = (char*)d_ws;
    unsigned short* x_bf  = (unsigned short*)(ws);                       // 8 MB
    unsigned short* wvt   = (unsigned short*)(ws + 8u  * 1024 * 1024);   // 2 MB
    unsigned short* wo_bf = (unsigned short*)(ws + 10u * 1024 * 1024);   // 2 MB
    unsigned short* m_bf  = (unsigned short*)(ws + 12u * 1024 * 1024);   // 2 MB
    float*          cvec  = (float*)(ws + 14u * 1024 * 1024);            // 4 KB

    // 1. x -> bf16 (4M elems)
    cast_f32_bf16<<<(MROWS * EDIM / 8 + 255) / 256, 256, 0, stream>>>(x, x_bf, MROWS * EDIM / 8);
    // 2. WvT[e,k] = bf16(Wqkv[vrow(k), e])
    build_wvt<<<dim3(16, 16), dim3(64, 4), 0, stream>>>(Wqkv, wvt);
    // 3. Wo -> bf16 (1M elems)
    cast_f32_bf16<<<(EDIM * EDIM / 8 + 255) / 256, 256, 0, stream>>>(Wo, wo_bf, EDIM * EDIM / 8);
    // 4. fused bias c = Wo @ bv + bo
    compute_c<<<EDIM, 64, 0, stream>>>(Wo, bqkv, bo, cvec);
    // 5. M = Wo @ Wv_sub  (bf16 out), C[i,e] = sum_k Wo[i,k] * WvT[e,k]
    gemm_bt<false, unsigned short><<<dim3(8, 8), 256, 0, stream>>>(
        wo_bf, wvt, m_bf, nullptr, EDIM, EDIM, EDIM);
    // 6. out = x @ M^T + c
    gemm_bt<true, float><<<dim3(32, 8), 256, 0, stream>>>(
        x_bf, m_bf, out, cvec, MROWS, EDIM, EDIM);
}